// Round 5
// baseline (469.963 us; speedup 1.0000x reference)
//
#include <hip/hip_runtime.h>
#include <math.h>

#define NB 8
#define NL 2048
#define ND 768
#define NH 1024
#define NR 3
#define NM (NB*NL)   // 16384 tokens
#define LS 32        // l-split for pooling kernels

typedef _Float16 h16;
typedef __attribute__((ext_vector_type(8))) _Float16 h16x8;
typedef __attribute__((ext_vector_type(4))) float f32x4;

#define ASCALE 4.0f
#define BSCALE 64.0f
#define INV_AB (1.0f/(ASCALE*BSCALE))

// ---- workspace layout (float offsets; all sections %4==0 -> 16B aligned) ----
enum : int {
  WS_MU     = 0,                     // [NM]
  WS_ISTD   = WS_MU + NM,            // [NM]
  WS_SCORES = WS_ISTD + NM,          // [NM]
  WS_RANKS  = WS_SCORES + NM,        // [NM]
  WS_LEFF   = WS_RANKS + NM,         // [8]
  WS_SMEAN  = WS_LEFF + 8,           // [8]
  WS_SISTD  = WS_SMEAN + 8,          // [8]
  WS_KF     = WS_SISTD + 8,          // [24]
  WS_GDEN   = WS_KF + 24,            // [24]
  WS_CBP    = WS_GDEN + 24,          // [8][NH] partial sum_k lnb[k]*w1[k][n]
  WS_SPART  = WS_CBP + 8*NH,         // [16][NM]  gemm score partials per (n-block, wn-half)
  WS_FPART  = WS_SPART + 16*NM,      // [LS][NB*ND]   full_rep partials
  WS_PPART  = WS_FPART + LS*NB*ND,   // [LS][NR*NB*ND] pred partials
  WS_RPART  = WS_PPART + LS*NR*NB*ND,// [4][NM]       rank sigmoid partials
  WS_POSP   = WS_RPART + 4*NM,       // [4][NM]       pos-count partials
  WS_FULL   = WS_POSP + 4*NM,        // [NB*ND]
  WS_PRED   = WS_FULL + NB*ND,       // [NR*NB*ND]
  WS_BTH    = WS_PRED + NR*NB*ND,    // f16 [NH][ND] hi of BSCALE*lg[k]*w1[k][n]
  WS_BTL    = WS_BTH + NH*ND/2,      // f16 [NH][ND] lo
  WS_END    = WS_BTL + NH*ND/2
};

__device__ __forceinline__ float block_sum256(float v) {
  __shared__ float tmp[4];
  __shared__ float res;
  int lane = threadIdx.x & 63;
  int w = threadIdx.x >> 6;
  #pragma unroll
  for (int o = 32; o > 0; o >>= 1) v += __shfl_down(v, o);
  if (lane == 0) tmp[w] = v;
  __syncthreads();
  if (threadIdx.x == 0) res = tmp[0] + tmp[1] + tmp[2] + tmp[3];
  __syncthreads();
  return res;
}

// RNE split f32 -> hi fp16 + lo fp16 (v - (float)hi is exact)
__device__ __forceinline__ void f16split(float v, h16& hi, h16& lo) {
  hi = (h16)v;
  lo = (h16)(v - (float)hi);
}

// L_eff[b]
__global__ void k_leff(const float* __restrict__ attn, float* __restrict__ ws) {
  int b = blockIdx.x, t = threadIdx.x;
  float s = 0.f;
  for (int l = t; l < NL; l += 256) s += attn[b*NL + l];
  float tot = block_sum256(s);
  if (t == 0) ws[WS_LEFF + b] = tot;
}

// per-token LN stats; wave per token, float4 loads, no LDS
__global__ void k_stats(const float* __restrict__ emb, const float* __restrict__ attn,
                        float* __restrict__ ws) {
  int w = threadIdx.x >> 6, l = threadIdx.x & 63;
  int m = blockIdx.x*4 + w;
  const float* x = emb + (size_t)m * ND;
  float a = attn[m];
  float4 v0 = *(const float4*)&x[l*4];
  float4 v1 = *(const float4*)&x[256 + l*4];
  float4 v2 = *(const float4*)&x[512 + l*4];
  float s = v0.x+v0.y+v0.z+v0.w + v1.x+v1.y+v1.z+v1.w + v2.x+v2.y+v2.z+v2.w;
  #pragma unroll
  for (int o = 1; o < 64; o <<= 1) s += __shfl_xor(s, o);
  float mu = a * s / (float)ND;
  float q = 0.f;
  float xs[12] = {v0.x,v0.y,v0.z,v0.w, v1.x,v1.y,v1.z,v1.w, v2.x,v2.y,v2.z,v2.w};
  #pragma unroll
  for (int e = 0; e < 12; ++e) { float d = xs[e]*a - mu; q = fmaf(d, d, q); }
  #pragma unroll
  for (int o = 1; o < 64; o <<= 1) q += __shfl_xor(q, o);
  if (l == 0) {
    ws[WS_MU + m] = mu;
    ws[WS_ISTD + m] = 1.f / sqrtf(q / (float)ND + 1e-5f);
  }
}

// full_rep raw sums, LS-way l-split
__global__ void k_fullpart(const float* __restrict__ emb, const float* __restrict__ attn,
                           float* __restrict__ ws) {
  int b = blockIdx.x, dc = blockIdx.y, ls = blockIdx.z;
  int d = dc*256 + threadIdx.x;
  float acc = 0.f;
  int l0 = ls * (NL/LS);
  for (int l = l0; l < l0 + NL/LS; ++l)
    acc = fmaf(emb[((size_t)(b*NL + l))*ND + d], attn[b*NL + l], acc);
  ws[WS_FPART + ls*(NB*ND) + b*ND + d] = acc;
}

// cbp[j][n] = sum_{k in chunk j} lnb[k]*w1[k][n]   (8-way k-split)
__global__ void k_cb(const float* __restrict__ w1, const float* __restrict__ lnb,
                     float* __restrict__ ws) {
  int n = blockIdx.x*256 + threadIdx.x;
  int j = blockIdx.y;
  float s = 0.f;
  for (int k = j*(ND/8); k < (j+1)*(ND/8); ++k)
    s = fmaf(lnb[k], w1[(size_t)k*NH + n], s);
  ws[WS_CBP + j*NH + n] = s;
}

// transpose + fold ln_g + scale + fp16-split W1: bT[n][k] = BSCALE*lg[k]*w1[k][n]
__global__ void k_splitB(const float* __restrict__ w1, const float* __restrict__ lng,
                         float* __restrict__ ws) {
  __shared__ float tile[32][33];
  int bk = blockIdx.x, bn = blockIdx.y, t = threadIdx.x;
  int i = t >> 5, j = t & 31;
  #pragma unroll
  for (int s = 0; s < 4; ++s)
    tile[i + 8*s][j] = w1[(size_t)(bk*32 + i + 8*s)*NH + bn*32 + j];
  __syncthreads();
  h16* bth = (h16*)(ws + WS_BTH);
  h16* btl = (h16*)(ws + WS_BTL);
  int kl = j;
  float lg = lng[bk*32 + kl] * BSCALE;
  #pragma unroll
  for (int s = 0; s < 4; ++s) {
    int nl = i + 8*s;
    int n = bn*32 + nl, k = bk*32 + kl;
    h16 hi, lo;
    f16split(tile[kl][nl] * lg, hi, lo);
    bth[(size_t)n*ND + k] = hi;
    btl[(size_t)n*ND + k] = lo;
  }
}

// A[16384,768] x W1'[768,1024] via scaled fp16x3 split MFMA; LN folded into
// A staging (lg/lb folded into B/cb); gelu.w2 fused epilogue.
// Each 128x128 block: 2x2 waves; per-row score partials are PER (n-block, wn)
// -> WS_SPART[16][NM] (round-3 bug: wn halves raced on one slot).
__global__ void __launch_bounds__(256) k_gemm(
    const float* __restrict__ emb, const float* __restrict__ attn,
    const float* __restrict__ b1, const float* __restrict__ w2,
    float* __restrict__ ws) {
  __shared__ h16 AsH[128][40], AsL[128][40], BsH[128][40], BsL[128][40];
  int t = threadIdx.x;
  int m0 = blockIdx.x * 128, n0 = blockIdx.y * 128;
  // staging coords: row = t>>1, k-half = (t&1)*16
  int ar = t >> 1, ak = (t & 1) * 16;
  float isv = ws[WS_ISTD + m0 + ar];
  float pco  = ASCALE * attn[m0 + ar] * isv;          // A' = fma(x, pco, mqco)
  float mqco = -ASCALE * ws[WS_MU + m0 + ar] * isv;
  // wave/frag coords
  int lane = t & 63, w = t >> 6, wm = w >> 1, wn = w & 1;
  int fr = lane & 15, g = lane >> 4;
  f32x4 acc[4][4];
  #pragma unroll
  for (int i = 0; i < 4; ++i)
    #pragma unroll
    for (int j = 0; j < 4; ++j) acc[i][j] = (f32x4){0.f, 0.f, 0.f, 0.f};
  const h16* bth = (const h16*)(ws + WS_BTH);
  const h16* btl = (const h16*)(ws + WS_BTL);

  for (int k0 = 0; k0 < ND; k0 += 32) {
    // ---- global loads + fp16 split (before barrier: overlaps prior MFMA) ----
    h16 hs[16], lo[16];
    #pragma unroll
    for (int i = 0; i < 4; ++i) {
      float4 x = *(const float4*)&emb[(size_t)(m0 + ar)*ND + k0 + ak + 4*i];
      float xs[4] = {x.x, x.y, x.z, x.w};
      #pragma unroll
      for (int e = 0; e < 4; ++e)
        f16split(fmaf(xs[e], pco, mqco), hs[4*i+e], lo[4*i+e]);
    }
    h16x8 bh0 = *(const h16x8*)&bth[(size_t)(n0 + ar)*ND + k0 + ak];
    h16x8 bh1 = *(const h16x8*)&bth[(size_t)(n0 + ar)*ND + k0 + ak + 8];
    h16x8 bl0 = *(const h16x8*)&btl[(size_t)(n0 + ar)*ND + k0 + ak];
    h16x8 bl1 = *(const h16x8*)&btl[(size_t)(n0 + ar)*ND + k0 + ak + 8];
    __syncthreads();   // prior phase done reading LDS
    *(h16x8*)&AsH[ar][ak]     = (h16x8){hs[0],hs[1],hs[2],hs[3],hs[4],hs[5],hs[6],hs[7]};
    *(h16x8*)&AsH[ar][ak + 8] = (h16x8){hs[8],hs[9],hs[10],hs[11],hs[12],hs[13],hs[14],hs[15]};
    *(h16x8*)&AsL[ar][ak]     = (h16x8){lo[0],lo[1],lo[2],lo[3],lo[4],lo[5],lo[6],lo[7]};
    *(h16x8*)&AsL[ar][ak + 8] = (h16x8){lo[8],lo[9],lo[10],lo[11],lo[12],lo[13],lo[14],lo[15]};
    *(h16x8*)&BsH[ar][ak]     = bh0;
    *(h16x8*)&BsH[ar][ak + 8] = bh1;
    *(h16x8*)&BsL[ar][ak]     = bl0;
    *(h16x8*)&BsL[ar][ak + 8] = bl1;
    __syncthreads();   // tiles ready
    // ---- fragments + MFMA (hi*hi + hi*lo + lo*hi; lo*lo ~2^-22, dropped) ----
    h16x8 ah[4], al[4];
    #pragma unroll
    for (int mi = 0; mi < 4; ++mi) {
      int r = wm*64 + mi*16 + fr;
      ah[mi] = *(const h16x8*)&AsH[r][g*8];
      al[mi] = *(const h16x8*)&AsL[r][g*8];
    }
    #pragma unroll
    for (int ni = 0; ni < 4; ++ni) {
      int c = wn*64 + ni*16 + fr;
      h16x8 bh = *(const h16x8*)&BsH[c][g*8];
      h16x8 bl = *(const h16x8*)&BsL[c][g*8];
      #pragma unroll
      for (int mi = 0; mi < 4; ++mi) {
        acc[mi][ni] = __builtin_amdgcn_mfma_f32_16x16x32_f16(ah[mi], bh, acc[mi][ni], 0, 0, 0);
        acc[mi][ni] = __builtin_amdgcn_mfma_f32_16x16x32_f16(ah[mi], bl, acc[mi][ni], 0, 0, 0);
        acc[mi][ni] = __builtin_amdgcn_mfma_f32_16x16x32_f16(al[mi], bh, acc[mi][ni], 0, 0, 0);
      }
    }
  }
  // ---- epilogue: h = acc/256 + b1 + cb; gelu exact; dot w2; reduce over cols ----
  float b1v[4], w2v[4];
  #pragma unroll
  for (int ni = 0; ni < 4; ++ni) {
    int c = n0 + wn*64 + ni*16 + fr;
    float cb = 0.f;
    #pragma unroll
    for (int j = 0; j < 8; ++j) cb += ws[WS_CBP + j*NH + c];
    b1v[ni] = b1[c] + cb;
    w2v[ni] = w2[c];
  }
  #pragma unroll
  for (int mi = 0; mi < 4; ++mi) {
    #pragma unroll
    for (int q = 0; q < 4; ++q) {
      float p = 0.f;
      #pragma unroll
      for (int ni = 0; ni < 4; ++ni) {
        float h = fmaf(acc[mi][ni][q], INV_AB, b1v[ni]);
        float ge = 0.5f * h * (1.f + erff(h * 0.70710678118654752f));
        p = fmaf(ge, w2v[ni], p);
      }
      p += __shfl_xor(p, 1);
      p += __shfl_xor(p, 2);
      p += __shfl_xor(p, 4);
      p += __shfl_xor(p, 8);
      if (fr == 0)
        ws[WS_SPART + (blockIdx.y*2 + wn)*NM + m0 + wm*64 + mi*16 + 4*g + q] = p;
    }
  }
}

// reduce 16 (n-block, wn) partials -> scores (+b2)
__global__ void k_scorered(float* __restrict__ ws, const float* __restrict__ b2) {
  int i = blockIdx.x*256 + threadIdx.x;
  float s = 0.f;
  #pragma unroll
  for (int j = 0; j < 16; ++j) s += ws[WS_SPART + j*NM + i];
  ws[WS_SCORES + i] = s + b2[0];
}

// masked mean/var of scores per batch
__global__ void k_scorestats(const float* __restrict__ attn, float* __restrict__ ws) {
  int b = blockIdx.x, t = threadIdx.x;
  float s = 0.f;
  for (int l = t; l < NL; l += 256) s += attn[b*NL + l] * ws[WS_SCORES + b*NL + l];
  float tot = block_sum256(s);
  float le = ws[WS_LEFF + b];
  float mean = tot / fmaxf(le, 1.f);
  float v = 0.f;
  for (int l = t; l < NL; l += 256) {
    float a = attn[b*NL + l];
    float d = ws[WS_SCORES + b*NL + l] - mean;
    v = fmaf(a * d, d, v);
  }
  float var = block_sum256(v) / fmaxf(le, 1.f);
  if (t == 0) { ws[WS_SMEAN + b] = mean; ws[WS_SISTD + b] = 1.f / sqrtf(var + 1e-6f); }
}

// rank partials over 512-j chunks
__global__ void k_rankpart(const float* __restrict__ attn, float* __restrict__ ws) {
  __shared__ float sCh[512];
  int b = blockIdx.x, c = blockIdx.y, js = blockIdx.z, t = threadIdx.x;
  float mean = ws[WS_SMEAN + b], istd = ws[WS_SISTD + b];
  for (int j = t; j < 512; j += 256) {
    int jj = js*512 + j;
    float a = attn[b*NL + jj];
    sCh[j] = (a != 0.f) ? (ws[WS_SCORES + b*NL + jj] - mean) * istd : -1e30f;
  }
  __syncthreads();
  int i = c*256 + t;
  float ai = attn[b*NL + i];
  float si = (ai != 0.f) ? (ws[WS_SCORES + b*NL + i] - mean) * istd : -1e30f;
  float acc = 0.f;
  #pragma unroll 4
  for (int j = 0; j < 512; ++j) {
    float u = (sCh[j] - si) * 2.0f;           // /tau, tau=0.5
    acc += 1.f / (1.f + __expf(-u));
  }
  ws[WS_RPART + js*NM + b*NL + i] = acc;
}

__global__ void k_rankred(const float* __restrict__ attn, float* __restrict__ ws) {
  int i = blockIdx.x*256 + threadIdx.x;
  float r = 0.5f + ws[WS_RPART + i] + ws[WS_RPART + NM + i]
                 + ws[WS_RPART + 2*NM + i] + ws[WS_RPART + 3*NM + i];
  ws[WS_RANKS + i] = (attn[i] != 0.f) ? r : 1e9f;
}

// k[r,b] and gate denominator
__global__ void k_gatedenom(const float* __restrict__ attn, const float* __restrict__ rhos,
                            float* __restrict__ ws) {
  int rb = blockIdx.x;
  int r = rb / NB, b = rb % NB;
  int t = threadIdx.x;
  float le = ws[WS_LEFF + b];
  float kf = rintf(rhos[r] * le);
  kf = (le > 0.f) ? fmaxf(kf, 1.f) : 0.f;
  float s = 0.f;
  for (int l = t; l < NL; l += 256) {
    float ri = ws[WS_RANKS + b*NL + l];
    s += attn[b*NL + l] / (1.f + __expf(ri - kf));
  }
  float tot = block_sum256(s);
  if (t == 0) { ws[WS_KF + rb] = kf; ws[WS_GDEN + rb] = fmaxf(tot, 1e-8f); }
}

// pos-count partials over 512-j chunks (stable tie-break by index)
__global__ void k_pospart(float* __restrict__ ws) {
  __shared__ float rCh[512];
  int b = blockIdx.x, c = blockIdx.y, js = blockIdx.z, t = threadIdx.x;
  for (int j = t; j < 512; j += 256) rCh[j] = ws[WS_RANKS + b*NL + js*512 + j];
  __syncthreads();
  int i = c*256 + t;
  float ri = ws[WS_RANKS + b*NL + i];
  int jbase = js*512;
  int cnt = 0;
  #pragma unroll 4
  for (int j = 0; j < 512; ++j) {
    float rj = rCh[j];
    cnt += (rj < ri) || (rj == ri && (jbase + j) < i);
  }
  ws[WS_POSP + js*NM + b*NL + i] = (float)cnt;
}

// z and g outputs
__global__ void k_zg(const float* __restrict__ attn, const float* __restrict__ ws,
                     float* __restrict__ out) {
  int b = blockIdx.x, c = blockIdx.y, t = threadIdx.x;
  int i = c*256 + t;
  float ri = ws[WS_RANKS + b*NL + i];
  int pos = (int)(ws[WS_POSP + b*NL + i] + ws[WS_POSP + NM + b*NL + i]
                + ws[WS_POSP + 2*NM + b*NL + i] + ws[WS_POSP + 3*NM + b*NL + i]);
  float ai = attn[b*NL + i];
  #pragma unroll
  for (int r = 0; r < NR; ++r) {
    float kf = ws[WS_KF + r*NB + b];
    float gd = ws[WS_GDEN + r*NB + b];
    float gate = ai / (1.f + __expf(ri - kf));
    float z = gate / gd * kf;
    float g = (pos < (int)kf) ? 1.f : 0.f;
    out[((size_t)(r*NB + b))*NL + i] = z;
    out[(size_t)NR*NB*NL + ((size_t)(r*NB + b))*NL + i] = g;
  }
}

// pred_rep raw sums: gather emb_table rows weighted by g; LS-way l-split
__global__ void k_poolpart(const int* __restrict__ ids, const float* __restrict__ tab,
                           const float* __restrict__ out, float* __restrict__ ws) {
  int b = blockIdx.x, dc = blockIdx.y, ls = blockIdx.z;
  int d = dc*256 + threadIdx.x;
  const float* g0 = out + (size_t)NR*NB*NL + ((size_t)(0*NB + b))*NL;
  const float* g1 = out + (size_t)NR*NB*NL + ((size_t)(1*NB + b))*NL;
  const float* g2 = out + (size_t)NR*NB*NL + ((size_t)(2*NB + b))*NL;
  float a0 = 0.f, a1 = 0.f, a2 = 0.f;
  int l0 = ls * (NL/LS);
  for (int l = l0; l < l0 + NL/LS; ++l) {
    float gg0 = g0[l], gg1 = g1[l], gg2 = g2[l];
    if (gg0 + gg1 + gg2 == 0.f) continue;
    float v = tab[(size_t)ids[b*NL + l]*ND + d];
    a0 = fmaf(gg0, v, a0); a1 = fmaf(gg1, v, a1); a2 = fmaf(gg2, v, a2);
  }
  float* pp = ws + WS_PPART + ls*(NR*NB*ND);
  pp[(0*NB + b)*ND + d] = a0;
  pp[(1*NB + b)*ND + d] = a1;
  pp[(2*NB + b)*ND + d] = a2;
}

// reduce LS-way partials for FULL and PRED
__global__ void k_prered(float* __restrict__ ws) {
  int idx = blockIdx.x*256 + threadIdx.x;   // 0..24575
  if (idx < NB*ND) {
    float s = 0.f;
    #pragma unroll 8
    for (int j = 0; j < LS; ++j) s += ws[WS_FPART + j*(NB*ND) + idx];
    ws[WS_FULL + idx] = s;
  } else {
    int p = idx - NB*ND;
    float s = 0.f;
    #pragma unroll 8
    for (int j = 0; j < LS; ++j) s += ws[WS_PPART + j*(NR*NB*ND) + p];
    ws[WS_PRED + p] = s;
  }
}

// cosine loss
__global__ void k_loss(float* __restrict__ ws, float* __restrict__ out) {
  int t = threadIdx.x;
  float lacc = 0.f;
  for (int rb = 0; rb < NR*NB; ++rb) {
    int b = rb % NB;
    float dn = fmaxf(ws[WS_KF + rb], 1.f);
    float le = fmaxf(ws[WS_LEFF + b], 1.f);
    float num = 0.f, p2 = 0.f, f2 = 0.f;
    for (int d = t; d < ND; d += 256) {
      float p = ws[WS_PRED + rb*ND + d] / dn;
      float f = ws[WS_FULL + b*ND + d] / le;
      num = fmaf(p, f, num); p2 = fmaf(p, p, p2); f2 = fmaf(f, f, f2);
    }
    num = block_sum256(num);
    p2 = block_sum256(p2);
    f2 = block_sum256(f2);
    if (t == 0)
      lacc += 1.f - num / (fmaxf(sqrtf(p2), 1e-8f) * fmaxf(sqrtf(f2), 1e-8f));
  }
  if (t == 0) out[(size_t)2*NR*NB*NL] = lacc / (float)(NR*NB);
}

extern "C" void kernel_launch(void* const* d_in, const int* in_sizes, int n_in,
                              void* d_out, int out_size, void* d_ws, size_t ws_size,
                              hipStream_t stream) {
  const int*   ids  = (const int*)d_in[0];
  const float* emb  = (const float*)d_in[1];
  const float* attn = (const float*)d_in[2];
  const float* rhos = (const float*)d_in[3];
  const float* lng  = (const float*)d_in[4];
  const float* lnb  = (const float*)d_in[5];
  const float* w1   = (const float*)d_in[6];
  const float* b1   = (const float*)d_in[7];
  const float* w2   = (const float*)d_in[8];
  const float* b2   = (const float*)d_in[9];
  const float* tab  = (const float*)d_in[10];
  float* out = (float*)d_out;
  float* ws  = (float*)d_ws;

  k_leff      <<<NB, 256, 0, stream>>>(attn, ws);
  k_stats     <<<NM/4, 256, 0, stream>>>(emb, attn, ws);
  k_fullpart  <<<dim3(NB, 3, LS), 256, 0, stream>>>(emb, attn, ws);
  k_cb        <<<dim3(NH/256, 8), 256, 0, stream>>>(w1, lnb, ws);
  k_splitB    <<<dim3(ND/32, NH/32), 256, 0, stream>>>(w1, lng, ws);
  k_gemm      <<<dim3(NM/128, NH/128), 256, 0, stream>>>(emb, attn, b1, w2, ws);
  k_scorered  <<<NM/256, 256, 0, stream>>>(ws, b2);
  k_scorestats<<<NB, 256, 0, stream>>>(attn, ws);
  k_rankpart  <<<dim3(NB, NL/256, 4), 256, 0, stream>>>(attn, ws);
  k_rankred   <<<NM/256, 256, 0, stream>>>(attn, ws);
  k_gatedenom <<<NR*NB, 256, 0, stream>>>(attn, rhos, ws);
  k_pospart   <<<dim3(NB, NL/256, 4), 256, 0, stream>>>(ws);
  k_zg        <<<dim3(NB, NL/256), 256, 0, stream>>>(attn, ws, out);
  k_poolpart  <<<dim3(NB, 3, LS), 256, 0, stream>>>(ids, tab, out, ws);
  k_prered    <<<(NB*ND + NR*NB*ND)/256, 256, 0, stream>>>(ws);
  k_loss      <<<1, 256, 0, stream>>>(ws, out);
}

// Round 7
// 452.723 us; speedup vs baseline: 1.0381x; 1.0381x over previous
//
#include <hip/hip_runtime.h>
#include <math.h>

#define NB 8
#define NL 2048
#define ND 768
#define NH 1024
#define NR 3
#define NM (NB*NL)   // 16384 tokens
#define LS 32        // l-split for pooling kernels
#define LOG2E  1.4426950408889634f
#define LOG2E2 2.8853900817779268f  // 2/tau_rank * log2(e), tau=0.5

typedef _Float16 h16;
typedef __attribute__((ext_vector_type(2))) _Float16 h16x2;
typedef __attribute__((ext_vector_type(8))) _Float16 h16x8;
typedef __attribute__((ext_vector_type(4))) float f32x4;

#define ASCALE 4.0f
#define BSCALE 64.0f
#define INV_AB (1.0f/(ASCALE*BSCALE))

// ---- workspace layout (float offsets; all sections %4==0 -> 16B aligned) ----
enum : int {
  WS_SCORES = 0,                     // [NM]
  WS_MU     = WS_SCORES + NM,        // [NM]
  WS_ISTD   = WS_MU + NM,            // [NM]
  WS_LEFF   = WS_ISTD + NM,          // [8]
  WS_SMEAN  = WS_LEFF + 8,           // [8]
  WS_SISTD  = WS_SMEAN + 8,          // [8]
  WS_KF     = WS_SISTD + 8,          // [24]
  WS_GDEN   = WS_KF + 24,            // [24]
  WS_LOSSP  = WS_GDEN + 24,          // [24]
  WS_CBP    = WS_LOSSP + 24,         // [24][NH] partial sum_k lnb[k]*w1[k][n]
  WS_SPART  = WS_CBP + 24*NH,        // [16][NM]  gemm score partials per (n-block, wn)
  WS_FPART  = WS_SPART + 16*NM,      // [LS][NB*ND]    full_rep partials
  WS_PPART  = WS_FPART + LS*NB*ND,   // [LS][NR*NB*ND] pred partials
  WS_RPART  = WS_PPART + LS*NR*NB*ND,// [4][NM]        rank sigmoid partials
  WS_POSP   = WS_RPART + 4*NM,       // [4][NM]        pos-count partials
  WS_BTH    = WS_POSP + 4*NM,        // f16 [NH][ND] hi of BSCALE*lg[k]*w1[k][n]
  WS_BTL    = WS_BTH + NH*ND/2,      // f16 [NH][ND] lo
  WS_END    = WS_BTL + NH*ND/2
};

__device__ __forceinline__ float block_sum256(float v) {
  __shared__ float tmp[4];
  __shared__ float res;
  int lane = threadIdx.x & 63;
  int w = threadIdx.x >> 6;
  #pragma unroll
  for (int o = 32; o > 0; o >>= 1) v += __shfl_down(v, o);
  if (lane == 0) tmp[w] = v;
  __syncthreads();
  if (threadIdx.x == 0) res = tmp[0] + tmp[1] + tmp[2] + tmp[3];
  __syncthreads();
  return res;
}

// packed split: hi = RTZ fp16 pair of (a,b); lo = RTZ fp16 of exact residuals
// (cvt_pkrtz returns __fp16 vector; element-cast to _Float16 is a no-op)
__device__ __forceinline__ void f16split2(float a, float b, h16x2& hi, h16x2& lo) {
  auto h = __builtin_amdgcn_cvt_pkrtz(a, b);
  float ra = a - (float)h[0];
  float rb = b - (float)h[1];
  auto l = __builtin_amdgcn_cvt_pkrtz(ra, rb);
  hi = (h16x2){(h16)h[0], (h16)h[1]};
  lo = (h16x2){(h16)l[0], (h16)l[1]};
}

__device__ __forceinline__ float fsig_exp2(float x) {  // 1/(1+2^x), ~1ulp
  return __builtin_amdgcn_rcpf(1.f + exp2f(x));
}

// per-token LN stats; wave per token, float4 loads, no LDS
__global__ void k_stats(const float* __restrict__ emb, const float* __restrict__ attn,
                        float* __restrict__ ws) {
  int w = threadIdx.x >> 6, l = threadIdx.x & 63;
  int m = blockIdx.x*4 + w;
  const float* x = emb + (size_t)m * ND;
  float a = attn[m];
  float4 v0 = *(const float4*)&x[l*4];
  float4 v1 = *(const float4*)&x[256 + l*4];
  float4 v2 = *(const float4*)&x[512 + l*4];
  float s = v0.x+v0.y+v0.z+v0.w + v1.x+v1.y+v1.z+v1.w + v2.x+v2.y+v2.z+v2.w;
  #pragma unroll
  for (int o = 1; o < 64; o <<= 1) s += __shfl_xor(s, o);
  float mu = a * s / (float)ND;
  float q = 0.f;
  float xs[12] = {v0.x,v0.y,v0.z,v0.w, v1.x,v1.y,v1.z,v1.w, v2.x,v2.y,v2.z,v2.w};
  #pragma unroll
  for (int e = 0; e < 12; ++e) { float d = xs[e]*a - mu; q = fmaf(d, d, q); }
  #pragma unroll
  for (int o = 1; o < 64; o <<= 1) q += __shfl_xor(q, o);
  if (l == 0) {
    ws[WS_MU + m] = mu;
    ws[WS_ISTD + m] = 1.f / sqrtf(q / (float)ND + 1e-5f);
  }
}

// full_rep raw sums, LS-way l-split
__global__ void k_fullpart(const float* __restrict__ emb, const float* __restrict__ attn,
                           float* __restrict__ ws) {
  int b = blockIdx.x, dc = blockIdx.y, ls = blockIdx.z;
  int d = dc*256 + threadIdx.x;
  float acc = 0.f;
  int l0 = ls * (NL/LS);
  for (int l = l0; l < l0 + NL/LS; ++l)
    acc = fmaf(emb[((size_t)(b*NL + l))*ND + d], attn[b*NL + l], acc);
  ws[WS_FPART + ls*(NB*ND) + b*ND + d] = acc;
}

// transpose + fold ln_g + scale + fp16-split W1 (bT[n][k] = BSCALE*lg[k]*w1[k][n]);
// fused: per-tile cb partial = sum_kl lnb[k]*w1[k][n]
__global__ void k_splitBcb(const float* __restrict__ w1, const float* __restrict__ lng,
                           const float* __restrict__ lnb, float* __restrict__ ws) {
  __shared__ float tile[32][33];
  int bk = blockIdx.x, bn = blockIdx.y, t = threadIdx.x;
  int i = t >> 5, j = t & 31;
  #pragma unroll
  for (int s = 0; s < 4; ++s)
    tile[i + 8*s][j] = w1[(size_t)(bk*32 + i + 8*s)*NH + bn*32 + j];
  __syncthreads();
  h16* bth = (h16*)(ws + WS_BTH);
  h16* btl = (h16*)(ws + WS_BTL);
  int kl = j;
  float lg = lng[bk*32 + kl] * BSCALE;
  #pragma unroll
  for (int s = 0; s < 4; ++s) {
    int nl = i + 8*s;
    int n = bn*32 + nl, k = bk*32 + kl;
    float v = tile[kl][nl] * lg;
    h16 hi = (h16)v;
    bth[(size_t)n*ND + k] = hi;
    btl[(size_t)n*ND + k] = (h16)(v - (float)hi);
  }
  if (t < 32) {   // cb partial for this k-chunk (tile is read-only since barrier)
    float s = 0.f;
    #pragma unroll
    for (int kl2 = 0; kl2 < 32; ++kl2)
      s = fmaf(lnb[bk*32 + kl2], tile[kl2][t], s);
    ws[WS_CBP + bk*NH + bn*32 + t] = s;
  }
}

// A[16384,768] x W1'[768,1024] via scaled fp16x3 split MFMA; LN folded into
// A staging (lg/lb folded into B/cb); gelu.w2 fused epilogue.
// pad 36 (36,864B x4 buffers = 147KB/CU for 4 resident blocks; banks balanced)
__global__ void __launch_bounds__(256) k_gemm(
    const float* __restrict__ emb, const float* __restrict__ attn,
    const float* __restrict__ b1, const float* __restrict__ w2,
    float* __restrict__ ws) {
  __shared__ h16 AsH[128][36], AsL[128][36], BsH[128][36], BsL[128][36];
  int t = threadIdx.x;
  int m0 = blockIdx.x * 128, n0 = blockIdx.y * 128;
  int ar = t >> 1, ak = (t & 1) * 16;   // staging: row, k-half
  float isv = ws[WS_ISTD + m0 + ar];
  float pco  = ASCALE * attn[m0 + ar] * isv;          // A' = fma(x, pco, mqco)
  float mqco = -ASCALE * ws[WS_MU + m0 + ar] * isv;
  int lane = t & 63, w = t >> 6, wm = w >> 1, wn = w & 1;
  int fr = lane & 15, g = lane >> 4;
  f32x4 acc[4][4];
  #pragma unroll
  for (int i = 0; i < 4; ++i)
    #pragma unroll
    for (int j = 0; j < 4; ++j) acc[i][j] = (f32x4){0.f, 0.f, 0.f, 0.f};
  const h16* bth = (const h16*)(ws + WS_BTH);
  const h16* btl = (const h16*)(ws + WS_BTL);

  for (int k0 = 0; k0 < ND; k0 += 32) {
    // ---- global loads + packed fp16 split (overlaps prior MFMA phase) ----
    h16 hs[16], lo[16];
    #pragma unroll
    for (int i = 0; i < 2; ++i) {
      float4 x0 = *(const float4*)&emb[(size_t)(m0 + ar)*ND + k0 + ak + 8*i];
      float4 x1 = *(const float4*)&emb[(size_t)(m0 + ar)*ND + k0 + ak + 8*i + 4];
      h16x2 h0, l0v, h1, l1, h2, l2, h3, l3;
      f16split2(fmaf(x0.x, pco, mqco), fmaf(x0.y, pco, mqco), h0, l0v);
      f16split2(fmaf(x0.z, pco, mqco), fmaf(x0.w, pco, mqco), h1, l1);
      f16split2(fmaf(x1.x, pco, mqco), fmaf(x1.y, pco, mqco), h2, l2);
      f16split2(fmaf(x1.z, pco, mqco), fmaf(x1.w, pco, mqco), h3, l3);
      hs[8*i+0]=h0[0]; hs[8*i+1]=h0[1]; hs[8*i+2]=h1[0]; hs[8*i+3]=h1[1];
      hs[8*i+4]=h2[0]; hs[8*i+5]=h2[1]; hs[8*i+6]=h3[0]; hs[8*i+7]=h3[1];
      lo[8*i+0]=l0v[0]; lo[8*i+1]=l0v[1]; lo[8*i+2]=l1[0]; lo[8*i+3]=l1[1];
      lo[8*i+4]=l2[0]; lo[8*i+5]=l2[1]; lo[8*i+6]=l3[0]; lo[8*i+7]=l3[1];
    }
    h16x8 bh0 = *(const h16x8*)&bth[(size_t)(n0 + ar)*ND + k0 + ak];
    h16x8 bh1 = *(const h16x8*)&bth[(size_t)(n0 + ar)*ND + k0 + ak + 8];
    h16x8 bl0 = *(const h16x8*)&btl[(size_t)(n0 + ar)*ND + k0 + ak];
    h16x8 bl1 = *(const h16x8*)&btl[(size_t)(n0 + ar)*ND + k0 + ak + 8];
    __syncthreads();   // prior phase done reading LDS
    *(h16x8*)&AsH[ar][ak]     = *(const h16x8*)&hs[0];
    *(h16x8*)&AsH[ar][ak + 8] = *(const h16x8*)&hs[8];
    *(h16x8*)&AsL[ar][ak]     = *(const h16x8*)&lo[0];
    *(h16x8*)&AsL[ar][ak + 8] = *(const h16x8*)&lo[8];
    *(h16x8*)&BsH[ar][ak]     = bh0;
    *(h16x8*)&BsH[ar][ak + 8] = bh1;
    *(h16x8*)&BsL[ar][ak]     = bl0;
    *(h16x8*)&BsL[ar][ak + 8] = bl1;
    __syncthreads();   // tiles ready
    // ---- fragments + MFMA (hi*hi + hi*lo + lo*hi; lo*lo ~2^-21, dropped) ----
    h16x8 ah[4], al[4];
    #pragma unroll
    for (int mi = 0; mi < 4; ++mi) {
      int r = wm*64 + mi*16 + fr;
      ah[mi] = *(const h16x8*)&AsH[r][g*8];
      al[mi] = *(const h16x8*)&AsL[r][g*8];
    }
    #pragma unroll
    for (int ni = 0; ni < 4; ++ni) {
      int c = wn*64 + ni*16 + fr;
      h16x8 bh = *(const h16x8*)&BsH[c][g*8];
      h16x8 bl = *(const h16x8*)&BsL[c][g*8];
      #pragma unroll
      for (int mi = 0; mi < 4; ++mi) {
        acc[mi][ni] = __builtin_amdgcn_mfma_f32_16x16x32_f16(ah[mi], bh, acc[mi][ni], 0, 0, 0);
        acc[mi][ni] = __builtin_amdgcn_mfma_f32_16x16x32_f16(ah[mi], bl, acc[mi][ni], 0, 0, 0);
        acc[mi][ni] = __builtin_amdgcn_mfma_f32_16x16x32_f16(al[mi], bh, acc[mi][ni], 0, 0, 0);
      }
    }
  }
  // ---- epilogue: h = acc/256 + b1 + cb; gelu exact; dot w2; reduce over cols ----
  float b1v[4], w2v[4];
  #pragma unroll
  for (int ni = 0; ni < 4; ++ni) {
    int c = n0 + wn*64 + ni*16 + fr;
    float cb = 0.f;
    #pragma unroll
    for (int j = 0; j < 24; ++j) cb += ws[WS_CBP + j*NH + c];
    b1v[ni] = b1[c] + cb;
    w2v[ni] = w2[c];
  }
  #pragma unroll
  for (int mi = 0; mi < 4; ++mi) {
    #pragma unroll
    for (int q = 0; q < 4; ++q) {
      float p = 0.f;
      #pragma unroll
      for (int ni = 0; ni < 4; ++ni) {
        float h = fmaf(acc[mi][ni][q], INV_AB, b1v[ni]);
        float ge = 0.5f * h * (1.f + erff(h * 0.70710678118654752f));
        p = fmaf(ge, w2v[ni], p);
      }
      p += __shfl_xor(p, 1);
      p += __shfl_xor(p, 2);
      p += __shfl_xor(p, 4);
      p += __shfl_xor(p, 8);
      if (fr == 0)
        ws[WS_SPART + (blockIdx.y*2 + wn)*NM + m0 + wm*64 + mi*16 + 4*g + q] = p;
    }
  }
}

// fused: scores = sum16 SPART + b2 -> WS_SCORES; leff; masked mean/var per b
__global__ void k_scorestats(const float* __restrict__ attn, const float* __restrict__ b2,
                             float* __restrict__ ws) {
  __shared__ float sS[NL];
  __shared__ float aS[NL];
  int b = blockIdx.x, t = threadIdx.x;
  float b2v = b2[0];
  float sa = 0.f, at = 0.f;
  for (int l = t; l < NL; l += 256) {
    float s = 0.f;
    #pragma unroll
    for (int j = 0; j < 16; ++j) s += ws[WS_SPART + j*NM + b*NL + l];
    s += b2v;
    ws[WS_SCORES + b*NL + l] = s;
    float a = attn[b*NL + l];
    sS[l] = s; aS[l] = a;
    at += a; sa = fmaf(a, s, sa);
  }
  float leff = block_sum256(at);      // syncs -> sS/aS complete
  float mean = block_sum256(sa) / fmaxf(leff, 1.f);
  float v = 0.f;
  for (int l = t; l < NL; l += 256) {
    float d = sS[l] - mean;
    v = fmaf(aS[l] * d, d, v);
  }
  float var = block_sum256(v) / fmaxf(leff, 1.f);
  if (t == 0) {
    ws[WS_LEFF + b] = leff;
    ws[WS_SMEAN + b] = mean;
    ws[WS_SISTD + b] = 1.f / sqrtf(var + 1e-6f);
  }
}

// rank partials over 512-j chunks; term = 1/(1+2^(zi-zj)), z = s_norm*2*log2e
__global__ void k_rankpart(const float* __restrict__ attn, float* __restrict__ ws) {
  __shared__ float sCh[512];
  int b = blockIdx.x, c = blockIdx.y, js = blockIdx.z, t = threadIdx.x;
  float mean = ws[WS_SMEAN + b], istd = ws[WS_SISTD + b] * LOG2E2;
  for (int j = t; j < 512; j += 256) {
    int jj = js*512 + j;
    float a = attn[b*NL + jj];
    sCh[j] = (a != 0.f) ? (ws[WS_SCORES + b*NL + jj] - mean) * istd : -2.9e30f;
  }
  __syncthreads();
  int i = c*256 + t;
  float ai = attn[b*NL + i];
  float zi = (ai != 0.f) ? (ws[WS_SCORES + b*NL + i] - mean) * istd : -2.9e30f;
  float acc = 0.f;
  #pragma unroll 4
  for (int j = 0; j < 512; ++j)
    acc += fsig_exp2(zi - sCh[j]);   // masked j: exp2(+inf)->inf -> 0; masked i: 1
  ws[WS_RPART + js*NM + b*NL + i] = acc;
}

// k[r,b] and gate denominator (rank summed inline from 4 RPART chunks)
__global__ void k_gatedenom(const float* __restrict__ attn, const float* __restrict__ rhos,
                            float* __restrict__ ws) {
  int rb = blockIdx.x;
  int r = rb / NB, b = rb % NB;
  int t = threadIdx.x;
  float le = ws[WS_LEFF + b];
  float kf = rintf(rhos[r] * le);
  kf = (le > 0.f) ? fmaxf(kf, 1.f) : 0.f;
  float s = 0.f;
  for (int l = t; l < NL; l += 256) {
    int i = b*NL + l;
    float ri = 0.5f + ws[WS_RPART + i] + ws[WS_RPART + NM + i]
                    + ws[WS_RPART + 2*NM + i] + ws[WS_RPART + 3*NM + i];
    s += attn[i] * fsig_exp2((ri - kf) * LOG2E);
  }
  float tot = block_sum256(s);
  if (t == 0) { ws[WS_KF + rb] = kf; ws[WS_GDEN + rb] = fmaxf(tot, 1e-8f); }
}

// pos-count partials over 512-j chunks (stable tie-break by index); rank inline
__global__ void k_pospart(const float* __restrict__ attn, float* __restrict__ ws) {
  __shared__ float rCh[512];
  int b = blockIdx.x, c = blockIdx.y, js = blockIdx.z, t = threadIdx.x;
  for (int j = t; j < 512; j += 256) {
    int jj = b*NL + js*512 + j;
    float rr = 0.5f + ws[WS_RPART + jj] + ws[WS_RPART + NM + jj]
                    + ws[WS_RPART + 2*NM + jj] + ws[WS_RPART + 3*NM + jj];
    rCh[j] = (attn[jj] != 0.f) ? rr : 1e9f;
  }
  __syncthreads();
  int i = c*256 + t, ii = b*NL + i;
  float ri = 0.5f + ws[WS_RPART + ii] + ws[WS_RPART + NM + ii]
                  + ws[WS_RPART + 2*NM + ii] + ws[WS_RPART + 3*NM + ii];
  ri = (attn[ii] != 0.f) ? ri : 1e9f;
  int jbase = js*512;
  int cnt = 0;
  #pragma unroll 4
  for (int j = 0; j < 512; ++j) {
    float rj = rCh[j];
    cnt += (rj < ri) || (rj == ri && (jbase + j) < i);
  }
  ws[WS_POSP + js*NM + ii] = (float)cnt;
}

// z and g outputs (rank inline)
__global__ void k_zg(const float* __restrict__ attn, const float* __restrict__ ws,
                     float* __restrict__ out) {
  int b = blockIdx.x, c = blockIdx.y, t = threadIdx.x;
  int i = c*256 + t, ii = b*NL + i;
  float ai = attn[ii];
  float ri = 0.5f + ws[WS_RPART + ii] + ws[WS_RPART + NM + ii]
                  + ws[WS_RPART + 2*NM + ii] + ws[WS_RPART + 3*NM + ii];
  ri = (ai != 0.f) ? ri : 1e9f;
  int pos = (int)(ws[WS_POSP + ii] + ws[WS_POSP + NM + ii]
                + ws[WS_POSP + 2*NM + ii] + ws[WS_POSP + 3*NM + ii]);
  #pragma unroll
  for (int r = 0; r < NR; ++r) {
    float kf = ws[WS_KF + r*NB + b];
    float gd = ws[WS_GDEN + r*NB + b];
    float gate = ai * fsig_exp2((ri - kf) * LOG2E);
    float z = gate / gd * kf;
    float g = (pos < (int)kf) ? 1.f : 0.f;
    out[((size_t)(r*NB + b))*NL + i] = z;
    out[(size_t)NR*NB*NL + ((size_t)(r*NB + b))*NL + i] = g;
  }
}

// pred_rep raw sums: gather emb_table rows weighted by g; LS-way l-split
__global__ void k_poolpart(const int* __restrict__ ids, const float* __restrict__ tab,
                           const float* __restrict__ out, float* __restrict__ ws) {
  int b = blockIdx.x, dc = blockIdx.y, ls = blockIdx.z;
  int d = dc*256 + threadIdx.x;
  const float* g0 = out + (size_t)NR*NB*NL + ((size_t)(0*NB + b))*NL;
  const float* g1 = out + (size_t)NR*NB*NL + ((size_t)(1*NB + b))*NL;
  const float* g2 = out + (size_t)NR*NB*NL + ((size_t)(2*NB + b))*NL;
  float a0 = 0.f, a1 = 0.f, a2 = 0.f;
  int l0 = ls * (NL/LS);
  for (int l = l0; l < l0 + NL/LS; ++l) {
    float gg0 = g0[l], gg1 = g1[l], gg2 = g2[l];
    if (gg0 + gg1 + gg2 == 0.f) continue;
    float v = tab[(size_t)ids[b*NL + l]*ND + d];
    a0 = fmaf(gg0, v, a0); a1 = fmaf(gg1, v, a1); a2 = fmaf(gg2, v, a2);
  }
  float* pp = ws + WS_PPART + ls*(NR*NB*ND);
  pp[(0*NB + b)*ND + d] = a0;
  pp[(1*NB + b)*ND + d] = a1;
  pp[(2*NB + b)*ND + d] = a2;
}

// per-(r,b) cosine-loss partial; partial reduces fused inline (32-way sums)
__global__ void k_lossp(float* __restrict__ ws) {
  int rb = blockIdx.x, t = threadIdx.x;
  int b = rb & 7;
  float dn = fmaxf(ws[WS_KF + rb], 1.f);
  float le = fmaxf(ws[WS_LEFF + b], 1.f);
  float num = 0.f, p2 = 0.f, f2 = 0.f;
  for (int d = t; d < ND; d += 256) {
    float ps = 0.f, fs = 0.f;
    #pragma unroll 8
    for (int j = 0; j < LS; ++j) {
      ps += ws[WS_PPART + j*(NR*NB*ND) + rb*ND + d];
      fs += ws[WS_FPART + j*(NB*ND) + b*ND + d];
    }
    float p = ps / dn, f = fs / le;
    num = fmaf(p, f, num); p2 = fmaf(p, p, p2); f2 = fmaf(f, f, f2);
  }
  num = block_sum256(num);
  p2 = block_sum256(p2);
  f2 = block_sum256(f2);
  if (t == 0)
    ws[WS_LOSSP + rb] = 1.f - num / (fmaxf(sqrtf(p2), 1e-8f) * fmaxf(sqrtf(f2), 1e-8f));
}

__global__ void k_losssum(const float* __restrict__ ws, float* __restrict__ out) {
  int t = threadIdx.x;
  float v = (t < NR*NB) ? ws[WS_LOSSP + t] : 0.f;
  #pragma unroll
  for (int o = 32; o > 0; o >>= 1) v += __shfl_down(v, o);
  if (t == 0) out[(size_t)2*NR*NB*NL] = v / (float)(NR*NB);
}

extern "C" void kernel_launch(void* const* d_in, const int* in_sizes, int n_in,
                              void* d_out, int out_size, void* d_ws, size_t ws_size,
                              hipStream_t stream) {
  const int*   ids  = (const int*)d_in[0];
  const float* emb  = (const float*)d_in[1];
  const float* attn = (const float*)d_in[2];
  const float* rhos = (const float*)d_in[3];
  const float* lng  = (const float*)d_in[4];
  const float* lnb  = (const float*)d_in[5];
  const float* w1   = (const float*)d_in[6];
  const float* b1   = (const float*)d_in[7];
  const float* w2   = (const float*)d_in[8];
  const float* b2   = (const float*)d_in[9];
  const float* tab  = (const float*)d_in[10];
  float* out = (float*)d_out;
  float* ws  = (float*)d_ws;

  k_stats     <<<NM/4, 256, 0, stream>>>(emb, attn, ws);
  k_fullpart  <<<dim3(NB, 3, LS), 256, 0, stream>>>(emb, attn, ws);
  k_splitBcb  <<<dim3(ND/32, NH/32), 256, 0, stream>>>(w1, lng, lnb, ws);
  k_gemm      <<<dim3(NM/128, NH/128), 256, 0, stream>>>(emb, attn, b1, w2, ws);
  k_scorestats<<<NB, 256, 0, stream>>>(attn, b2, ws);
  k_rankpart  <<<dim3(NB, NL/256, 4), 256, 0, stream>>>(attn, ws);
  k_gatedenom <<<NR*NB, 256, 0, stream>>>(attn, rhos, ws);
  k_pospart   <<<dim3(NB, NL/256, 4), 256, 0, stream>>>(attn, ws);
  k_zg        <<<dim3(NB, NL/256), 256, 0, stream>>>(attn, ws, out);
  k_poolpart  <<<dim3(NB, 3, LS), 256, 0, stream>>>(ids, tab, out, ws);
  k_lossp     <<<NR*NB, 256, 0, stream>>>(ws);
  k_losssum   <<<1, 64, 0, stream>>>(ws, out);
}

// Round 8
// 413.891 us; speedup vs baseline: 1.1355x; 1.0938x over previous
//
#include <hip/hip_runtime.h>
#include <math.h>

#define NB 8
#define NL 2048
#define ND 768
#define NH 1024
#define NR 3
#define NM (NB*NL)   // 16384 tokens
#define LS 32        // l-split for pooling kernels
#define LOG2E  1.4426950408889634f
#define LOG2E2 2.8853900817779268f  // 2/tau_rank * log2(e), tau=0.5

typedef _Float16 h16;
typedef __attribute__((ext_vector_type(4))) _Float16 h16x4;
typedef __attribute__((ext_vector_type(8))) _Float16 h16x8;
typedef __attribute__((ext_vector_type(4))) float f32x4;

#define ASCALE 4.0f
#define BSCALE 64.0f
#define INV_AB (1.0f/(ASCALE*BSCALE))

// ---- workspace layout (float offsets; all sections %4==0 -> 16B aligned) ----
enum : int {
  WS_SCORES = 0,                     // [NM]
  WS_MU     = WS_SCORES + NM,        // [NM]  (fallback path only)
  WS_ISTD   = WS_MU + NM,            // [NM]  (fallback path only)
  WS_LEFF   = WS_ISTD + NM,          // [8]
  WS_SMEAN  = WS_LEFF + 8,           // [8]
  WS_SISTD  = WS_SMEAN + 8,          // [8]
  WS_KF     = WS_SISTD + 8,          // [24]
  WS_GDEN   = WS_KF + 24,            // [24]
  WS_LOSSP  = WS_GDEN + 24,          // [24]
  WS_CBP    = WS_LOSSP + 24,         // [24][NH] partial sum_k lnb[k]*w1[k][n]
  WS_SPART  = WS_CBP + 24*NH,        // [16][NM]  gemm score partials per (n-block, wn)
  WS_FPART  = WS_SPART + 16*NM,      // [LS][NB*ND]    full_rep partials
  WS_PPART  = WS_FPART + LS*NB*ND,   // [LS][NR*NB*ND] pred partials
  WS_RPART  = WS_PPART + LS*NR*NB*ND,// [4][NM]        rank sigmoid partials
  WS_POSP   = WS_RPART + 4*NM,       // [4][NM]        pos-count partials
  WS_BT0    = WS_POSP + 4*NM,        // f16 [NH*ND]: fallback = row [n][k] hi; big = frag hi
  WS_BT1    = WS_BT0 + NH*ND/2,      // f16 [NH*ND]: lo
  WS_SMALL_END = WS_BT1 + NH*ND/2,   // fallback path needs this much
  WS_ATH    = WS_SMALL_END,          // f16 [NM][ND] hi of ASCALE*LN(x)   (big path)
  WS_ATL    = WS_ATH + NM*ND/2,      // f16 [NM][ND] lo
  WS_END    = WS_ATL + NM*ND/2
};

__device__ __forceinline__ float block_sum256(float v) {
  __shared__ float tmp[4];
  __shared__ float res;
  int lane = threadIdx.x & 63;
  int w = threadIdx.x >> 6;
  #pragma unroll
  for (int o = 32; o > 0; o >>= 1) v += __shfl_down(v, o);
  if (lane == 0) tmp[w] = v;
  __syncthreads();
  if (threadIdx.x == 0) res = tmp[0] + tmp[1] + tmp[2] + tmp[3];
  __syncthreads();
  return res;
}

// scalar RNE split f32 -> hi fp16 + lo fp16 (residual is exact in f32)
__device__ __forceinline__ void f16split(float v, h16& hi, h16& lo) {
  hi = (h16)v;
  lo = (h16)(v - (float)hi);
}

__device__ __forceinline__ float fsig_exp2(float x) {  // 1/(1+2^x), ~1ulp
  return __builtin_amdgcn_rcpf(1.f + exp2f(x));
}

// ============================ BIG-WS PATH ============================

// per-token LN stats + write A' = ASCALE*LN(x) as fp16 hi/lo rows [m][k]
__global__ void k_statsA(const float* __restrict__ emb, const float* __restrict__ attn,
                         float* __restrict__ ws) {
  int w = threadIdx.x >> 6, l = threadIdx.x & 63;
  int m = blockIdx.x*4 + w;
  const float* x = emb + (size_t)m * ND;
  float a = attn[m];
  float4 v0 = *(const float4*)&x[l*4];
  float4 v1 = *(const float4*)&x[256 + l*4];
  float4 v2 = *(const float4*)&x[512 + l*4];
  float s = v0.x+v0.y+v0.z+v0.w + v1.x+v1.y+v1.z+v1.w + v2.x+v2.y+v2.z+v2.w;
  #pragma unroll
  for (int o = 1; o < 64; o <<= 1) s += __shfl_xor(s, o);
  float mu = a * s / (float)ND;
  float q = 0.f;
  float xs[12] = {v0.x,v0.y,v0.z,v0.w, v1.x,v1.y,v1.z,v1.w, v2.x,v2.y,v2.z,v2.w};
  #pragma unroll
  for (int e = 0; e < 12; ++e) { float d = xs[e]*a - mu; q = fmaf(d, d, q); }
  #pragma unroll
  for (int o = 1; o < 64; o <<= 1) q += __shfl_xor(q, o);
  float istd = 1.f / sqrtf(q / (float)ND + 1e-5f);
  float pco  = ASCALE * a * istd;
  float mqco = -ASCALE * mu * istd;
  h16* ath = (h16*)(ws + WS_ATH);
  h16* atl = (h16*)(ws + WS_ATL);
  #pragma unroll
  for (int c = 0; c < 3; ++c) {
    h16x4 hi4, lo4;
    #pragma unroll
    for (int e = 0; e < 4; ++e) {
      float v = fmaf(xs[c*4 + e], pco, mqco);
      h16 hi, lo;
      f16split(v, hi, lo);
      hi4[e] = hi; lo4[e] = lo;
    }
    size_t off = (size_t)m*ND + c*256 + l*4;
    *(h16x4*)&ath[off] = hi4;
    *(h16x4*)&atl[off] = lo4;
  }
}

// W1 -> fragment layout: BF[n/16][kb][lane][e] = BSCALE*lg[k]*w1[k][n],
// lane = (n&15) + 16*g, k = kb*32 + g*8 + e  (identical mapping to the
// verified LDS fragment reads).  + fused cb partial.
__global__ void k_splitBfrag(const float* __restrict__ w1, const float* __restrict__ lng,
                             const float* __restrict__ lnb, float* __restrict__ ws) {
  __shared__ float tile[32][33];
  int bk = blockIdx.x, bn = blockIdx.y, t = threadIdx.x;
  int i = t >> 5, j = t & 31;
  #pragma unroll
  for (int s = 0; s < 4; ++s)
    tile[i + 8*s][j] = w1[(size_t)(bk*32 + i + 8*s)*NH + bn*32 + j];
  __syncthreads();
  h16* bth = (h16*)(ws + WS_BT0);
  h16* btl = (h16*)(ws + WS_BT1);
  int n_local = t & 31, g2 = (t >> 5) & 3, hl = t >> 7;
  int n = bn*32 + n_local;
  int nb16 = n >> 4;
  int lanef = (n & 15) + 16*g2;
  size_t base = ((size_t)(nb16*24 + bk)*64 + lanef)*8;
  h16x8 out8;
  #pragma unroll
  for (int e = 0; e < 8; ++e) {
    int kl = g2*8 + e;
    float v = tile[kl][n_local] * (lng[bk*32 + kl] * BSCALE);
    h16 hi, lo;
    f16split(v, hi, lo);
    out8[e] = hl ? lo : hi;
  }
  *(h16x8*)&((hl ? btl : bth)[base]) = out8;
  if (t < 32) {   // cb partial for this k-chunk
    float s = 0.f;
    #pragma unroll
    for (int kl2 = 0; kl2 < 32; ++kl2)
      s = fmaf(lnb[bk*32 + kl2], tile[kl2][t], s);
    ws[WS_CBP + bk*NH + bn*32 + t] = s;
  }
}

// fragment-streaming GEMM: no LDS, no barriers. Per wave: 64x64 output tile,
// per K-step 16 coalesced 16B fragment loads + 48 MFMA.
__global__ void __launch_bounds__(256) k_gemm_frag(
    const float* __restrict__ b1, const float* __restrict__ w2,
    float* __restrict__ ws) {
  int t = threadIdx.x;
  int lane = t & 63, w = t >> 6, wm = w >> 1, wn = w & 1;
  int fr = lane & 15, g = lane >> 4;
  int nb = blockIdx.x, mb = blockIdx.y;    // grid (8, 128): n fastest -> A-tile L2/L3 reuse
  int m0 = mb*128, n0 = nb*128;
  const h16* __restrict__ ath = (const h16*)(ws + WS_ATH);
  const h16* __restrict__ atl = (const h16*)(ws + WS_ATL);
  const h16* __restrict__ bfh = (const h16*)(ws + WS_BT0);
  const h16* __restrict__ bfl = (const h16*)(ws + WS_BT1);
  size_t abase = (size_t)(m0 + wm*64 + fr)*ND + g*8;
  size_t bbase = ((size_t)(nb*8 + wn*4)*24*64 + lane)*8;
  f32x4 acc[4][4];
  #pragma unroll
  for (int i = 0; i < 4; ++i)
    #pragma unroll
    for (int j = 0; j < 4; ++j) acc[i][j] = (f32x4){0.f, 0.f, 0.f, 0.f};

  #pragma unroll 1
  for (int kb = 0; kb < 24; ++kb) {
    h16x8 ah[4], al[4], bh[4], bl[4];
    #pragma unroll
    for (int mi = 0; mi < 4; ++mi) {
      ah[mi] = *(const h16x8*)&ath[abase + (size_t)mi*(16*ND) + kb*32];
      al[mi] = *(const h16x8*)&atl[abase + (size_t)mi*(16*ND) + kb*32];
    }
    #pragma unroll
    for (int ni = 0; ni < 4; ++ni) {
      bh[ni] = *(const h16x8*)&bfh[bbase + ((size_t)ni*24 + kb)*(64*8)];
      bl[ni] = *(const h16x8*)&bfl[bbase + ((size_t)ni*24 + kb)*(64*8)];
    }
    #pragma unroll
    for (int ni = 0; ni < 4; ++ni)
      #pragma unroll
      for (int mi = 0; mi < 4; ++mi) {
        acc[mi][ni] = __builtin_amdgcn_mfma_f32_16x16x32_f16(ah[mi], bh[ni], acc[mi][ni], 0, 0, 0);
        acc[mi][ni] = __builtin_amdgcn_mfma_f32_16x16x32_f16(ah[mi], bl[ni], acc[mi][ni], 0, 0, 0);
        acc[mi][ni] = __builtin_amdgcn_mfma_f32_16x16x32_f16(al[mi], bh[ni], acc[mi][ni], 0, 0, 0);
      }
  }
  // epilogue: h = acc/256 + b1 + cb; gelu exact; dot w2; reduce over 16 cols
  float b1v[4], w2v[4];
  #pragma unroll
  for (int ni = 0; ni < 4; ++ni) {
    int c = n0 + wn*64 + ni*16 + fr;
    float cb = 0.f;
    #pragma unroll
    for (int j = 0; j < 24; ++j) cb += ws[WS_CBP + j*NH + c];
    b1v[ni] = b1[c] + cb;
    w2v[ni] = w2[c];
  }
  #pragma unroll
  for (int mi = 0; mi < 4; ++mi) {
    #pragma unroll
    for (int q = 0; q < 4; ++q) {
      float p = 0.f;
      #pragma unroll
      for (int ni = 0; ni < 4; ++ni) {
        float h = fmaf(acc[mi][ni][q], INV_AB, b1v[ni]);
        float ge = 0.5f * h * (1.f + erff(h * 0.70710678118654752f));
        p = fmaf(ge, w2v[ni], p);
      }
      p += __shfl_xor(p, 1);
      p += __shfl_xor(p, 2);
      p += __shfl_xor(p, 4);
      p += __shfl_xor(p, 8);
      if (fr == 0)
        ws[WS_SPART + (nb*2 + wn)*NM + m0 + wm*64 + mi*16 + 4*g + q] = p;
    }
  }
}

// ========================== FALLBACK PATH (round-5 structure) ==========================

__global__ void k_stats(const float* __restrict__ emb, const float* __restrict__ attn,
                        float* __restrict__ ws) {
  int w = threadIdx.x >> 6, l = threadIdx.x & 63;
  int m = blockIdx.x*4 + w;
  const float* x = emb + (size_t)m * ND;
  float a = attn[m];
  float4 v0 = *(const float4*)&x[l*4];
  float4 v1 = *(const float4*)&x[256 + l*4];
  float4 v2 = *(const float4*)&x[512 + l*4];
  float s = v0.x+v0.y+v0.z+v0.w + v1.x+v1.y+v1.z+v1.w + v2.x+v2.y+v2.z+v2.w;
  #pragma unroll
  for (int o = 1; o < 64; o <<= 1) s += __shfl_xor(s, o);
  float mu = a * s / (float)ND;
  float q = 0.f;
  float xs[12] = {v0.x,v0.y,v0.z,v0.w, v1.x,v1.y,v1.z,v1.w, v2.x,v2.y,v2.z,v2.w};
  #pragma unroll
  for (int e = 0; e < 12; ++e) { float d = xs[e]*a - mu; q = fmaf(d, d, q); }
  #pragma unroll
  for (int o = 1; o < 64; o <<= 1) q += __shfl_xor(q, o);
  if (l == 0) {
    ws[WS_MU + m] = mu;
    ws[WS_ISTD + m] = 1.f / sqrtf(q / (float)ND + 1e-5f);
  }
}

__global__ void k_splitBcb(const float* __restrict__ w1, const float* __restrict__ lng,
                           const float* __restrict__ lnb, float* __restrict__ ws) {
  __shared__ float tile[32][33];
  int bk = blockIdx.x, bn = blockIdx.y, t = threadIdx.x;
  int i = t >> 5, j = t & 31;
  #pragma unroll
  for (int s = 0; s < 4; ++s)
    tile[i + 8*s][j] = w1[(size_t)(bk*32 + i + 8*s)*NH + bn*32 + j];
  __syncthreads();
  h16* bth = (h16*)(ws + WS_BT0);
  h16* btl = (h16*)(ws + WS_BT1);
  int kl = j;
  float lg = lng[bk*32 + kl] * BSCALE;
  #pragma unroll
  for (int s = 0; s < 4; ++s) {
    int nl = i + 8*s;
    int n = bn*32 + nl, k = bk*32 + kl;
    float v = tile[kl][nl] * lg;
    h16 hi, lo;
    f16split(v, hi, lo);
    bth[(size_t)n*ND + k] = hi;
    btl[(size_t)n*ND + k] = lo;
  }
  if (t < 32) {
    float s = 0.f;
    #pragma unroll
    for (int kl2 = 0; kl2 < 32; ++kl2)
      s = fmaf(lnb[bk*32 + kl2], tile[kl2][t], s);
    ws[WS_CBP + bk*NH + bn*32 + t] = s;
  }
}

__global__ void __launch_bounds__(256) k_gemm_fb(
    const float* __restrict__ emb, const float* __restrict__ attn,
    const float* __restrict__ b1, const float* __restrict__ w2,
    float* __restrict__ ws) {
  __shared__ h16 AsH[128][40], AsL[128][40], BsH[128][40], BsL[128][40];
  int t = threadIdx.x;
  int m0 = blockIdx.x * 128, n0 = blockIdx.y * 128;
  int ar = t >> 1, ak = (t & 1) * 16;
  float isv = ws[WS_ISTD + m0 + ar];
  float pco  = ASCALE * attn[m0 + ar] * isv;
  float mqco = -ASCALE * ws[WS_MU + m0 + ar] * isv;
  int lane = t & 63, w = t >> 6, wm = w >> 1, wn = w & 1;
  int fr = lane & 15, g = lane >> 4;
  f32x4 acc[4][4];
  #pragma unroll
  for (int i = 0; i < 4; ++i)
    #pragma unroll
    for (int j = 0; j < 4; ++j) acc[i][j] = (f32x4){0.f, 0.f, 0.f, 0.f};
  const h16* bth = (const h16*)(ws + WS_BT0);
  const h16* btl = (const h16*)(ws + WS_BT1);

  for (int k0 = 0; k0 < ND; k0 += 32) {
    h16 hs[16], lo[16];
    #pragma unroll
    for (int i = 0; i < 4; ++i) {
      float4 x = *(const float4*)&emb[(size_t)(m0 + ar)*ND + k0 + ak + 4*i];
      float xv[4] = {x.x, x.y, x.z, x.w};
      #pragma unroll
      for (int e = 0; e < 4; ++e)
        f16split(fmaf(xv[e], pco, mqco), hs[4*i+e], lo[4*i+e]);
    }
    h16x8 bh0 = *(const h16x8*)&bth[(size_t)(n0 + ar)*ND + k0 + ak];
    h16x8 bh1 = *(const h16x8*)&bth[(size_t)(n0 + ar)*ND + k0 + ak + 8];
    h16x8 bl0 = *(const h16x8*)&btl[(size_t)(n0 + ar)*ND + k0 + ak];
    h16x8 bl1 = *(const h16x8*)&btl[(size_t)(n0 + ar)*ND + k0 + ak + 8];
    __syncthreads();
    *(h16x8*)&AsH[ar][ak]     = *(const h16x8*)&hs[0];
    *(h16x8*)&AsH[ar][ak + 8] = *(const h16x8*)&hs[8];
    *(h16x8*)&AsL[ar][ak]     = *(const h16x8*)&lo[0];
    *(h16x8*)&AsL[ar][ak + 8] = *(const h16x8*)&lo[8];
    *(h16x8*)&BsH[ar][ak]     = bh0;
    *(h16x8*)&BsH[ar][ak + 8] = bh1;
    *(h16x8*)&BsL[ar][ak]     = bl0;
    *(h16x8*)&BsL[ar][ak + 8] = bl1;
    __syncthreads();
    h16x8 ah[4], al[4];
    #pragma unroll
    for (int mi = 0; mi < 4; ++mi) {
      int r = wm*64 + mi*16 + fr;
      ah[mi] = *(const h16x8*)&AsH[r][g*8];
      al[mi] = *(const h16x8*)&AsL[r][g*8];
    }
    #pragma unroll
    for (int ni = 0; ni < 4; ++ni) {
      int c = wn*64 + ni*16 + fr;
      h16x8 bh = *(const h16x8*)&BsH[c][g*8];
      h16x8 bl = *(const h16x8*)&BsL[c][g*8];
      #pragma unroll
      for (int mi = 0; mi < 4; ++mi) {
        acc[mi][ni] = __builtin_amdgcn_mfma_f32_16x16x32_f16(ah[mi], bh, acc[mi][ni], 0, 0, 0);
        acc[mi][ni] = __builtin_amdgcn_mfma_f32_16x16x32_f16(ah[mi], bl, acc[mi][ni], 0, 0, 0);
        acc[mi][ni] = __builtin_amdgcn_mfma_f32_16x16x32_f16(al[mi], bh, acc[mi][ni], 0, 0, 0);
      }
    }
  }
  float b1v[4], w2v[4];
  #pragma unroll
  for (int ni = 0; ni < 4; ++ni) {
    int c = n0 + wn*64 + ni*16 + fr;
    float cb = 0.f;
    #pragma unroll
    for (int j = 0; j < 24; ++j) cb += ws[WS_CBP + j*NH + c];
    b1v[ni] = b1[c] + cb;
    w2v[ni] = w2[c];
  }
  #pragma unroll
  for (int mi = 0; mi < 4; ++mi) {
    #pragma unroll
    for (int q = 0; q < 4; ++q) {
      float p = 0.f;
      #pragma unroll
      for (int ni = 0; ni < 4; ++ni) {
        float h = fmaf(acc[mi][ni][q], INV_AB, b1v[ni]);
        float ge = 0.5f * h * (1.f + erff(h * 0.70710678118654752f));
        p = fmaf(ge, w2v[ni], p);
      }
      p += __shfl_xor(p, 1);
      p += __shfl_xor(p, 2);
      p += __shfl_xor(p, 4);
      p += __shfl_xor(p, 8);
      if (fr == 0)
        ws[WS_SPART + (blockIdx.y*2 + wn)*NM + m0 + wm*64 + mi*16 + 4*g + q] = p;
    }
  }
}

// ========================== SHARED TAIL ==========================

__global__ void k_fullpart(const float* __restrict__ emb, const float* __restrict__ attn,
                           float* __restrict__ ws) {
  int b = blockIdx.x, dc = blockIdx.y, ls = blockIdx.z;
  int d = dc*256 + threadIdx.x;
  float acc = 0.f;
  int l0 = ls * (NL/LS);
  for (int l = l0; l < l0 + NL/LS; ++l)
    acc = fmaf(emb[((size_t)(b*NL + l))*ND + d], attn[b*NL + l], acc);
  ws[WS_FPART + ls*(NB*ND) + b*ND + d] = acc;
}

__global__ void k_scorestats(const float* __restrict__ attn, const float* __restrict__ b2,
                             float* __restrict__ ws) {
  __shared__ float sS[NL];
  __shared__ float aS[NL];
  int b = blockIdx.x, t = threadIdx.x;
  float b2v = b2[0];
  float sa = 0.f, at = 0.f;
  for (int l = t; l < NL; l += 256) {
    float s = 0.f;
    #pragma unroll
    for (int j = 0; j < 16; ++j) s += ws[WS_SPART + j*NM + b*NL + l];
    s += b2v;
    ws[WS_SCORES + b*NL + l] = s;
    float a = attn[b*NL + l];
    sS[l] = s; aS[l] = a;
    at += a; sa = fmaf(a, s, sa);
  }
  float leff = block_sum256(at);
  float mean = block_sum256(sa) / fmaxf(leff, 1.f);
  float v = 0.f;
  for (int l = t; l < NL; l += 256) {
    float d = sS[l] - mean;
    v = fmaf(aS[l] * d, d, v);
  }
  float var = block_sum256(v) / fmaxf(leff, 1.f);
  if (t == 0) {
    ws[WS_LEFF + b] = leff;
    ws[WS_SMEAN + b] = mean;
    ws[WS_SISTD + b] = 1.f / sqrtf(var + 1e-6f);
  }
}

__global__ void k_rankpart(const float* __restrict__ attn, float* __restrict__ ws) {
  __shared__ float sCh[512];
  int b = blockIdx.x, c = blockIdx.y, js = blockIdx.z, t = threadIdx.x;
  float mean = ws[WS_SMEAN + b], istd = ws[WS_SISTD + b] * LOG2E2;
  for (int j = t; j < 512; j += 256) {
    int jj = js*512 + j;
    float a = attn[b*NL + jj];
    sCh[j] = (a != 0.f) ? (ws[WS_SCORES + b*NL + jj] - mean) * istd : -2.9e30f;
  }
  __syncthreads();
  int i = c*256 + t;
  float ai = attn[b*NL + i];
  float zi = (ai != 0.f) ? (ws[WS_SCORES + b*NL + i] - mean) * istd : -2.9e30f;
  float acc = 0.f;
  #pragma unroll 4
  for (int j = 0; j < 512; ++j)
    acc += fsig_exp2(zi - sCh[j]);
  ws[WS_RPART + js*NM + b*NL + i] = acc;
}

__global__ void k_gatedenom(const float* __restrict__ attn, const float* __restrict__ rhos,
                            float* __restrict__ ws) {
  int rb = blockIdx.x;
  int r = rb / NB, b = rb % NB;
  int t = threadIdx.x;
  float le = ws[WS_LEFF + b];
  float kf = rintf(rhos[r] * le);
  kf = (le > 0.f) ? fmaxf(kf, 1.f) : 0.f;
  float s = 0.f;
  for (int l = t; l < NL; l += 256) {
    int i = b*NL + l;
    float ri = 0.5f + ws[WS_RPART + i] + ws[WS_RPART + NM + i]
                    + ws[WS_RPART + 2*NM + i] + ws[WS_RPART + 3*NM + i];
    s += attn[i] * fsig_exp2((ri - kf) * LOG2E);
  }
  float tot = block_sum256(s);
  if (t == 0) { ws[WS_KF + rb] = kf; ws[WS_GDEN + rb] = fmaxf(tot, 1e-8f); }
}

__global__ void k_pospart(const float* __restrict__ attn, float* __restrict__ ws) {
  __shared__ float rCh[512];
  int b = blockIdx.x, c = blockIdx.y, js = blockIdx.z, t = threadIdx.x;
  for (int j = t; j < 512; j += 256) {
    int jj = b*NL + js*512 + j;
    float rr = 0.5f + ws[WS_RPART + jj] + ws[WS_RPART + NM + jj]
                    + ws[WS_RPART + 2*NM + jj] + ws[WS_RPART + 3*NM + jj];
    rCh[j] = (attn[jj] != 0.f) ? rr : 1e9f;
  }
  __syncthreads();
  int i = c*256 + t, ii = b*NL + i;
  float ri = 0.5f + ws[WS_RPART + ii] + ws[WS_RPART + NM + ii]
                  + ws[WS_RPART + 2*NM + ii] + ws[WS_RPART + 3*NM + ii];
  ri = (attn[ii] != 0.f) ? ri : 1e9f;
  int jbase = js*512;
  int cnt = 0;
  #pragma unroll 4
  for (int j = 0; j < 512; ++j) {
    float rj = rCh[j];
    cnt += (rj < ri) || (rj == ri && (jbase + j) < i);
  }
  ws[WS_POSP + js*NM + ii] = (float)cnt;
}

__global__ void k_zg(const float* __restrict__ attn, const float* __restrict__ ws,
                     float* __restrict__ out) {
  int b = blockIdx.x, c = blockIdx.y, t = threadIdx.x;
  int i = c*256 + t, ii = b*NL + i;
  float ai = attn[ii];
  float ri = 0.5f + ws[WS_RPART + ii] + ws[WS_RPART + NM + ii]
                  + ws[WS_RPART + 2*NM + ii] + ws[WS_RPART + 3*NM + ii];
  ri = (ai != 0.f) ? ri : 1e9f;
  int pos = (int)(ws[WS_POSP + ii] + ws[WS_POSP + NM + ii]
                + ws[WS_POSP + 2*NM + ii] + ws[WS_POSP + 3*NM + ii]);
  #pragma unroll
  for (int r = 0; r < NR; ++r) {
    float kf = ws[WS_KF + r*NB + b];
    float gd = ws[WS_GDEN + r*NB + b];
    float gate = ai * fsig_exp2((ri - kf) * LOG2E);
    float z = gate / gd * kf;
    float g = (pos < (int)kf) ? 1.f : 0.f;
    out[((size_t)(r*NB + b))*NL + i] = z;
    out[(size_t)NR*NB*NL + ((size_t)(r*NB + b))*NL + i] = g;
  }
}

__global__ void k_poolpart(const int* __restrict__ ids, const float* __restrict__ tab,
                           const float* __restrict__ out, float* __restrict__ ws) {
  int b = blockIdx.x, dc = blockIdx.y, ls = blockIdx.z;
  int d = dc*256 + threadIdx.x;
  const float* g0 = out + (size_t)NR*NB*NL + ((size_t)(0*NB + b))*NL;
  const float* g1 = out + (size_t)NR*NB*NL + ((size_t)(1*NB + b))*NL;
  const float* g2 = out + (size_t)NR*NB*NL + ((size_t)(2*NB + b))*NL;
  float a0 = 0.f, a1 = 0.f, a2 = 0.f;
  int l0 = ls * (NL/LS);
  for (int l = l0; l < l0 + NL/LS; ++l) {
    float gg0 = g0[l], gg1 = g1[l], gg2 = g2[l];
    if (gg0 + gg1 + gg2 == 0.f) continue;
    float v = tab[(size_t)ids[b*NL + l]*ND + d];
    a0 = fmaf(gg0, v, a0); a1 = fmaf(gg1, v, a1); a2 = fmaf(gg2, v, a2);
  }
  float* pp = ws + WS_PPART + ls*(NR*NB*ND);
  pp[(0*NB + b)*ND + d] = a0;
  pp[(1*NB + b)*ND + d] = a1;
  pp[(2*NB + b)*ND + d] = a2;
}

__global__ void k_lossp(float* __restrict__ ws) {
  int rb = blockIdx.x, t = threadIdx.x;
  int b = rb & 7;
  float dn = fmaxf(ws[WS_KF + rb], 1.f);
  float le = fmaxf(ws[WS_LEFF + b], 1.f);
  float num = 0.f, p2 = 0.f, f2 = 0.f;
  for (int d = t; d < ND; d += 256) {
    float ps = 0.f, fs = 0.f;
    #pragma unroll 8
    for (int j = 0; j < LS; ++j) {
      ps += ws[WS_PPART + j*(NR*NB*ND) + rb*ND + d];
      fs += ws[WS_FPART + j*(NB*ND) + b*ND + d];
    }
    float p = ps / dn, f = fs / le;
    num = fmaf(p, f, num); p2 = fmaf(p, p, p2); f2 = fmaf(f, f, f2);
  }
  num = block_sum256(num);
  p2 = block_sum256(p2);
  f2 = block_sum256(f2);
  if (t == 0)
    ws[WS_LOSSP + rb] = 1.f - num / (fmaxf(sqrtf(p2), 1e-8f) * fmaxf(sqrtf(f2), 1e-8f));
}

__global__ void k_losssum(const float* __restrict__ ws, float* __restrict__ out) {
  int t = threadIdx.x;
  float v = (t < NR*NB) ? ws[WS_LOSSP + t] : 0.f;
  #pragma unroll
  for (int o = 32; o > 0; o >>= 1) v += __shfl_down(v, o);
  if (t == 0) out[(size_t)2*NR*NB*NL] = v / (float)(NR*NB);
}

extern "C" void kernel_launch(void* const* d_in, const int* in_sizes, int n_in,
                              void* d_out, int out_size, void* d_ws, size_t ws_size,
                              hipStream_t stream) {
  const int*   ids  = (const int*)d_in[0];
  const float* emb  = (const float*)d_in[1];
  const float* attn = (const float*)d_in[2];
  const float* rhos = (const float*)d_in[3];
  const float* lng  = (const float*)d_in[4];
  const float* lnb  = (const float*)d_in[5];
  const float* w1   = (const float*)d_in[6];
  const float* b1   = (const float*)d_in[7];
  const float* w2   = (const float*)d_in[8];
  const float* b2   = (const float*)d_in[9];
  const float* tab  = (const float*)d_in[10];
  float* out = (float*)d_out;
  float* ws  = (float*)d_ws;

  bool big = ws_size >= (size_t)WS_END * sizeof(float);  // constant across calls

  if (big) {
    k_statsA   <<<NM/4, 256, 0, stream>>>(emb, attn, ws);
    k_fullpart <<<dim3(NB, 3, LS), 256, 0, stream>>>(emb, attn, ws);
    k_splitBfrag<<<dim3(ND/32, NH/32), 256, 0, stream>>>(w1, lng, lnb, ws);
    k_gemm_frag<<<dim3(NH/128, NM/128), 256, 0, stream>>>(b1, w2, ws);
  } else {
    k_stats    <<<NM/4, 256, 0, stream>>>(emb, attn, ws);
    k_fullpart <<<dim3(NB, 3, LS), 256, 0, stream>>>(emb, attn, ws);
    k_splitBcb <<<dim3(ND/32, NH/32), 256, 0, stream>>>(w1, lng, lnb, ws);
    k_gemm_fb  <<<dim3(NM/128, NH/128), 256, 0, stream>>>(emb, attn, b1, w2, ws);
  }
  k_scorestats<<<NB, 256, 0, stream>>>(attn, b2, ws);
  k_rankpart  <<<dim3(NB, NL/256, 4), 256, 0, stream>>>(attn, ws);
  k_gatedenom <<<NR*NB, 256, 0, stream>>>(attn, rhos, ws);
  k_pospart   <<<dim3(NB, NL/256, 4), 256, 0, stream>>>(attn, ws);
  k_zg        <<<dim3(NB, NL/256), 256, 0, stream>>>(attn, ws, out);
  k_poolpart  <<<dim3(NB, 3, LS), 256, 0, stream>>>(ids, tab, out, ws);
  k_lossp     <<<NR*NB, 256, 0, stream>>>(ws);
  k_losssum   <<<1, 64, 0, stream>>>(ws, out);
}